// Round 2
// baseline (285.374 us; speedup 1.0000x reference)
//
#include <hip/hip_runtime.h>
#include <math.h>

#define BB 4
#define CC 256
#define NN 4096
#define DQ 32
#define LOG2E 1.44269504f

typedef _Float16 half8 __attribute__((ext_vector_type(8)));
typedef _Float16 half4 __attribute__((ext_vector_type(4)));
typedef float float4v __attribute__((ext_vector_type(4)));
typedef float float2v __attribute__((ext_vector_type(2)));

// ---------------- prep: W -> f16 (log2e folded into Wq/bq) ----------------
// Wh[320][256] f16: rows 0-31 Wq*log2e, 32-63 Wk, 64-319 Wv. bh[320] f32.
__global__ __launch_bounds__(64) void prep_kernel(
    const float* __restrict__ Wq, const float* __restrict__ bq,
    const float* __restrict__ Wk, const float* __restrict__ bk,
    const float* __restrict__ Wv, const float* __restrict__ bv,
    _Float16* __restrict__ Wh, float* __restrict__ bh)
{
    int o = blockIdx.x, t = threadIdx.x;
    const float* src; float scale = 1.0f, bias;
    if (o < DQ)            { src = Wq + o * CC;        scale = LOG2E; bias = bq[o] * LOG2E; }
    else if (o < 2 * DQ)   { src = Wk + (o - DQ) * CC;                bias = bk[o - DQ]; }
    else                   { src = Wv + (o - 2 * DQ) * CC;            bias = bv[o - 2 * DQ]; }
    float4 v = *(const float4*)(src + t * 4);
    half4 h = { (_Float16)(v.x * scale), (_Float16)(v.y * scale),
                (_Float16)(v.z * scale), (_Float16)(v.w * scale) };
    *(half4*)(Wh + o * CC + t * 4) = h;
    if (t == 0) bh[o] = bias;
}

// ---------------- proj: MFMA GEMM, all 320 outputs x 32-pixel tile ----------------
__global__ __launch_bounds__(256) void proj_kernel(
    const float* __restrict__ x, const _Float16* __restrict__ Wh,
    const float* __restrict__ bh,
    _Float16* __restrict__ Qt, _Float16* __restrict__ Kt,
    _Float16* __restrict__ Vh)
{
    __shared__ _Float16 xl[32 * 256];     // [n][c], chunk-of-8 XOR swizzle: chunk' = (c>>3) ^ n
    __shared__ _Float16 os_qk[32 * 72];   // [n][o<64 + pad]
    __shared__ _Float16 os_v[256 * 40];   // [c][n + pad]

    const int tid = threadIdx.x;
    const int lane = tid & 63, w = tid >> 6;
    const int i16 = lane & 15, q = lane >> 4;
    const int n0 = blockIdx.x * 32, b = blockIdx.y;

    // stage x tile transposed to f16 [n][c] with swizzle
    const float* xb = x + (size_t)b * CC * NN + n0;
    #pragma unroll
    for (int u = 0; u < 8; ++u) {
        int idx = u * 256 + tid;
        int c = idx >> 3, n4 = idx & 7;
        float4 v = *(const float4*)(xb + (size_t)c * NN + n4 * 4);
        int chunk = c >> 3, cl = c & 7;
        float vv[4] = {v.x, v.y, v.z, v.w};
        #pragma unroll
        for (int e = 0; e < 4; ++e) {
            int n = n4 * 4 + e;
            xl[n * 256 + ((chunk ^ n) * 8) + cl] = (_Float16)vv[e];
        }
    }

    // bias init (C-layout: reg r <-> row o offset r)
    float4v acc[5][2];
    const int obase = 80 * w;
    #pragma unroll
    for (int ot = 0; ot < 5; ++ot) {
        float4 b4 = *(const float4*)(bh + obase + 16 * ot + 4 * q);
        #pragma unroll
        for (int nt = 0; nt < 2; ++nt)
            acc[ot][nt] = (float4v){b4.x, b4.y, b4.z, b4.w};
    }
    __syncthreads();

    // K loop: 8 steps of 32 channels
    #pragma unroll
    for (int k = 0; k < 8; ++k) {
        half8 af[5], bf[2];
        #pragma unroll
        for (int ot = 0; ot < 5; ++ot)
            af[ot] = *(const half8*)(Wh + (size_t)(obase + 16 * ot + i16) * CC + k * 32 + 8 * q);
        #pragma unroll
        for (int nt = 0; nt < 2; ++nt) {
            int n = 16 * nt + i16;
            bf[nt] = *(const half8*)&xl[n * 256 + (((4 * k + q) ^ n) * 8)];
        }
        #pragma unroll
        for (int ot = 0; ot < 5; ++ot)
            #pragma unroll
            for (int nt = 0; nt < 2; ++nt)
                acc[ot][nt] = __builtin_amdgcn_mfma_f32_16x16x32_f16(af[ot], bf[nt], acc[ot][nt], 0, 0, 0);
    }

    // epilogue: write D into transpose buffers
    #pragma unroll
    for (int ot = 0; ot < 5; ++ot) {
        int og = obase + 16 * ot;
        #pragma unroll
        for (int nt = 0; nt < 2; ++nt) {
            int n = 16 * nt + i16;
            if (og < 64) {
                half4 hv = { (_Float16)acc[ot][nt][0], (_Float16)acc[ot][nt][1],
                             (_Float16)acc[ot][nt][2], (_Float16)acc[ot][nt][3] };
                *(half4*)&os_qk[n * 72 + og + 4 * q] = hv;
            } else {
                int cb = og - 64 + 4 * q;
                #pragma unroll
                for (int r = 0; r < 4; ++r)
                    os_v[(cb + r) * 40 + n] = (_Float16)acc[ot][nt][r];
            }
        }
    }
    __syncthreads();

    // coalesced global stores
    _Float16* Qtb = Qt + (size_t)b * NN * DQ;
    _Float16* Ktb = Kt + (size_t)b * NN * DQ;
    {
        int n = tid >> 3, p = tid & 7;
        half8 hv = *(const half8*)&os_qk[n * 72 + 8 * p];
        if (p < 4) *(half8*)(Qtb + (size_t)(n0 + n) * DQ + 8 * p) = hv;
        else       *(half8*)(Ktb + (size_t)(n0 + n) * DQ + 8 * (p - 4)) = hv;
    }
    _Float16* Vb = Vh + (size_t)b * CC * NN;
    #pragma unroll
    for (int u = 0; u < 4; ++u) {
        int c = u * 64 + (tid >> 2), p = tid & 3;
        half8 hv = *(const half8*)&os_v[c * 40 + 8 * p];
        *(half8*)(Vb + (size_t)c * NN + n0 + 8 * p) = hv;
    }
}

// ---------------- attn: fully fused flash attention (online softmax) ----------------
// Block: 32 queries x 128 channels, 4 waves. 2 barriers/iter, K/V double-buffered:
//   phase1: stage tile t+1 (buf^1) || S-MFMA from buf || strip stats+exp -> ps/st
//   B1; phase2: combine strip stats, rescale O, scale pb by beta, PV-MFMA; B2.
// Safety: ps/st written pre-B1(t), read post-B1(t); next write is post-B2(t).
//   buf^1 written pre-B1(t); read from t+1 (post-B2(t)). buf read pre-B2(t);
//   overwritten at t+1 phase1 (post-B2(t)).
__global__ __launch_bounds__(256) void attn_kernel(
    const float* __restrict__ x,
    const _Float16* __restrict__ Qt, const _Float16* __restrict__ Kt,
    const _Float16* __restrict__ Vh,
    float* __restrict__ out)
{
    __shared__ _Float16 k_lds[2][64 * 32];   // [j][d], d-chunk ^= (j&3)
    __shared__ _Float16 v_lds[2][128 * 64];  // [c][j], j-chunk ^= (c&7)
    __shared__ _Float16 ps[32 * 72];         // P': [i][j + pad], values <= 1
    __shared__ float    st[32][10];          // per query: [2w]=m_strip, [2w+1]=l_strip (pad->conflict-free)

    const int tid = threadIdx.x;
    const int w = tid >> 6, lane = tid & 63;
    const int i16 = lane & 15, q = lane >> 4;
    const int i0 = blockIdx.x * 32, cs = blockIdx.y, b = blockIdx.z;
    const int c0 = cs * 128;

    const _Float16* Ktb = Kt + (size_t)b * NN * DQ;
    const _Float16* Vb  = Vh + (size_t)b * CC * NN + (size_t)c0 * NN;

    half8 qb[2];
    {
        const _Float16* Qtb = Qt + (size_t)b * NN * DQ;
        qb[0] = *(const half8*)(Qtb + (size_t)(i0 + i16) * DQ + 8 * q);
        qb[1] = *(const half8*)(Qtb + (size_t)(i0 + 16 + i16) * DQ + 8 * q);
    }

    float4v O[2][2];
    #pragma unroll
    for (int ct = 0; ct < 2; ++ct)
        #pragma unroll
        for (int it = 0; it < 2; ++it)
            O[ct][it] = (float4v){0.f, 0.f, 0.f, 0.f};
    float m_run[2] = {-INFINITY, -INFINITY};
    float l_run[2] = {0.f, 0.f};

    // staging addresses
    const int jK = tid >> 2, dgK = tid & 3;      // K: 1 half8/thread
    const int cbV = tid >> 3, jgV = tid & 7;     // V: 4 half8/thread
    const int kaddr = jK * 32 + ((dgK ^ (jK & 3)) * 8);
    int vaddr[4];
    #pragma unroll
    for (int u = 0; u < 4; ++u) {
        int c = u * 32 + cbV;
        vaddr[u] = c * 64 + ((jgV ^ (c & 7)) * 8);
    }

    // prologue: tile 0 staged into buf 0; tile 1 in regs
    half8 kv, vv[4];
    kv = *(const half8*)(Ktb + (size_t)jK * DQ + 8 * dgK);
    #pragma unroll
    for (int u = 0; u < 4; ++u)
        vv[u] = *(const half8*)(Vb + (size_t)(u * 32 + cbV) * NN + 8 * jgV);
    *(half8*)&k_lds[0][kaddr] = kv;
    #pragma unroll
    for (int u = 0; u < 4; ++u)
        *(half8*)&v_lds[0][vaddr[u]] = vv[u];
    kv = *(const half8*)(Ktb + (size_t)(64 + jK) * DQ + 8 * dgK);
    #pragma unroll
    for (int u = 0; u < 4; ++u)
        vv[u] = *(const half8*)(Vb + (size_t)(u * 32 + cbV) * NN + 64 + 8 * jgV);
    __syncthreads();

    for (int t = 0; t < 64; ++t) {
        const int cur = t & 1;

        // ---- phase 1: stage next tile (other buffer) + S + strip stats ----
        if (t < 63) {
            *(half8*)&k_lds[cur ^ 1][kaddr] = kv;
            #pragma unroll
            for (int u = 0; u < 4; ++u)
                *(half8*)&v_lds[cur ^ 1][vaddr[u]] = vv[u];
        }
        {
            int j = 16 * w + i16;
            half8 ka = *(const half8*)&k_lds[cur][j * 32 + ((q ^ (j & 3)) * 8)];
            #pragma unroll
            for (int it = 0; it < 2; ++it) {
                float4v z = {0.f, 0.f, 0.f, 0.f};
                float4v s = __builtin_amdgcn_mfma_f32_16x16x32_f16(ka, qb[it], z, 0, 0, 0);
                float mx = fmaxf(fmaxf(s[0], s[1]), fmaxf(s[2], s[3]));
                mx = fmaxf(mx, __shfl_xor(mx, 16));
                mx = fmaxf(mx, __shfl_xor(mx, 32));
                float p0 = exp2f(s[0] - mx), p1 = exp2f(s[1] - mx);
                float p2 = exp2f(s[2] - mx), p3 = exp2f(s[3] - mx);
                float sm = (p0 + p1) + (p2 + p3);
                sm += __shfl_xor(sm, 16);
                sm += __shfl_xor(sm, 32);
                half4 hv = { (_Float16)p0, (_Float16)p1, (_Float16)p2, (_Float16)p3 };
                *(half4*)&ps[(16 * it + i16) * 72 + 16 * w + 4 * q] = hv;
                if (q == 0) {
                    st[16 * it + i16][2 * w]     = mx;
                    st[16 * it + i16][2 * w + 1] = sm;
                }
            }
        }
        // prefetch tile t+2 into regs (latency spans a whole iteration)
        if (t < 62) {
            int jn = (t + 2) * 64;
            kv = *(const half8*)(Ktb + (size_t)(jn + jK) * DQ + 8 * dgK);
            #pragma unroll
            for (int u = 0; u < 4; ++u)
                vv[u] = *(const half8*)(Vb + (size_t)(u * 32 + cbV) * NN + jn + 8 * jgV);
        }
        __syncthreads();   // B1: ps + st + staged tile ready

        // ---- phase 2: stats combine, rescale, PV ----
        half8 pb[2][2];
        #pragma unroll
        for (int ks = 0; ks < 2; ++ks)
            #pragma unroll
            for (int it = 0; it < 2; ++it)
                pb[ks][it] = *(const half8*)&ps[(16 * it + i16) * 72 + 32 * ks + 8 * q];

        #pragma unroll
        for (int it = 0; it < 2; ++it) {
            const float* sr = &st[16 * it + i16][0];
            float2v a0 = *(const float2v*)&sr[0];  // m0,l0
            float2v a1 = *(const float2v*)&sr[2];  // m1,l1
            float2v a2 = *(const float2v*)&sr[4];  // m2,l2
            float2v a3 = *(const float2v*)&sr[6];  // m3,l3
            float mt = fmaxf(fmaxf(a0[0], a1[0]), fmaxf(a2[0], a3[0]));
            float mn = fmaxf(m_run[it], mt);
            float al = exp2f(m_run[it] - mn);   // == 1.0 exactly when unchanged
            float lt = a0[1] * exp2f(a0[0] - mn) + a1[1] * exp2f(a1[0] - mn)
                     + a2[1] * exp2f(a2[0] - mn) + a3[1] * exp2f(a3[0] - mn);
            l_run[it] = l_run[it] * al + lt;
            m_run[it] = mn;
            O[0][it] *= al;
            O[1][it] *= al;
            // beta per pb fragment: strip(ks,q) = 2ks + (q>>1)
            float msA = (q & 2) ? a1[0] : a0[0];
            float msB = (q & 2) ? a3[0] : a2[0];
            _Float16 bA = (_Float16)exp2f(msA - mn);
            _Float16 bB = (_Float16)exp2f(msB - mn);
            pb[0][it] *= bA;
            pb[1][it] *= bB;
        }

        __builtin_amdgcn_s_setprio(1);
        #pragma unroll
        for (int ct = 0; ct < 2; ++ct) {
            int c = 32 * w + 16 * ct + i16;
            #pragma unroll
            for (int ks = 0; ks < 2; ++ks) {
                int g = 4 * ks + q;
                half8 va = *(const half8*)&v_lds[cur][c * 64 + ((g ^ (c & 7)) * 8)];
                #pragma unroll
                for (int it = 0; it < 2; ++it)
                    O[ct][it] = __builtin_amdgcn_mfma_f32_16x16x32_f16(va, pb[ks][it], O[ct][it], 0, 0, 0);
            }
        }
        __builtin_amdgcn_s_setprio(0);
        __syncthreads();   // B2: PV + ps/st reads done
    }

    // epilogue: O * (1/l) + residual
    float linv[2] = { 1.0f / l_run[0], 1.0f / l_run[1] };
    const float* xb = x + (size_t)b * CC * NN;
    float* ob = out + (size_t)b * CC * NN;
    #pragma unroll
    for (int ct = 0; ct < 2; ++ct)
        #pragma unroll
        for (int it = 0; it < 2; ++it)
            #pragma unroll
            for (int r = 0; r < 4; ++r) {
                int c = c0 + 32 * w + 16 * ct + 4 * q + r;
                size_t idx = (size_t)c * NN + i0 + 16 * it + i16;
                ob[idx] = xb[idx] + O[ct][it][r] * linv[it];
            }
}

extern "C" void kernel_launch(void* const* d_in, const int* in_sizes, int n_in,
                              void* d_out, int out_size, void* d_ws, size_t ws_size,
                              hipStream_t stream) {
    const float* x  = (const float*)d_in[0];
    const float* Wq = (const float*)d_in[1];
    const float* bq = (const float*)d_in[2];
    const float* Wk = (const float*)d_in[3];
    const float* bk = (const float*)d_in[4];
    const float* Wv = (const float*)d_in[5];
    const float* bv = (const float*)d_in[6];
    float* out = (float*)d_out;

    char* ws = (char*)d_ws;
    _Float16* Wh = (_Float16*)(ws);                 // 320*256*2 = 163840
    float*    bh = (float*)(ws + 163840);           // 1280
    _Float16* Qt = (_Float16*)(ws + 262144);        // 4*4096*32*2 = 1 MB
    _Float16* Kt = (_Float16*)(ws + 1310720);       // 1 MB
    _Float16* Vh = (_Float16*)(ws + 2359296);       // 4*256*4096*2 = 8 MB

    prep_kernel<<<dim3(320), 64, 0, stream>>>(Wq, bq, Wk, bk, Wv, bv, Wh, bh);
    proj_kernel<<<dim3(NN / 32, BB), 256, 0, stream>>>(x, Wh, bh, Qt, Kt, Vh);
    attn_kernel<<<dim3(NN / 32, 2, BB), 256, 0, stream>>>(x, Qt, Kt, Vh, out);
}

// Round 3
// 196.259 us; speedup vs baseline: 1.4541x; 1.4541x over previous
//
#include <hip/hip_runtime.h>
#include <math.h>

#define BB 4
#define CC 256
#define NN 4096
#define DQ 32
#define LOG2E 1.44269504f

typedef _Float16 half8 __attribute__((ext_vector_type(8)));
typedef _Float16 half4 __attribute__((ext_vector_type(4)));
typedef float float4v __attribute__((ext_vector_type(4)));

// ---------------- prep: W -> f16 (log2e folded into Wq/bq) ----------------
__global__ __launch_bounds__(64) void prep_kernel(
    const float* __restrict__ Wq, const float* __restrict__ bq,
    const float* __restrict__ Wk, const float* __restrict__ bk,
    const float* __restrict__ Wv, const float* __restrict__ bv,
    _Float16* __restrict__ Wh, float* __restrict__ bh)
{
    int o = blockIdx.x, t = threadIdx.x;
    const float* src; float scale = 1.0f, bias;
    if (o < DQ)            { src = Wq + o * CC;        scale = LOG2E; bias = bq[o] * LOG2E; }
    else if (o < 2 * DQ)   { src = Wk + (o - DQ) * CC;                bias = bk[o - DQ]; }
    else                   { src = Wv + (o - 2 * DQ) * CC;            bias = bv[o - 2 * DQ]; }
    float4 v = *(const float4*)(src + t * 4);
    half4 h = { (_Float16)(v.x * scale), (_Float16)(v.y * scale),
                (_Float16)(v.z * scale), (_Float16)(v.w * scale) };
    *(half4*)(Wh + o * CC + t * 4) = h;
    if (t == 0) bh[o] = bias;
}

// ---------------- proj: MFMA GEMM, all 320 outputs x 32-pixel tile ----------------
__global__ __launch_bounds__(256) void proj_kernel(
    const float* __restrict__ x, const _Float16* __restrict__ Wh,
    const float* __restrict__ bh,
    _Float16* __restrict__ Qt, _Float16* __restrict__ Kt,
    _Float16* __restrict__ Vh)
{
    __shared__ _Float16 xl[32 * 256];
    __shared__ _Float16 os_qk[32 * 72];
    __shared__ _Float16 os_v[256 * 40];

    const int tid = threadIdx.x;
    const int lane = tid & 63, w = tid >> 6;
    const int i16 = lane & 15, q = lane >> 4;
    const int n0 = blockIdx.x * 32, b = blockIdx.y;

    const float* xb = x + (size_t)b * CC * NN + n0;
    #pragma unroll
    for (int u = 0; u < 8; ++u) {
        int idx = u * 256 + tid;
        int c = idx >> 3, n4 = idx & 7;
        float4 v = *(const float4*)(xb + (size_t)c * NN + n4 * 4);
        int chunk = c >> 3, cl = c & 7;
        float vv[4] = {v.x, v.y, v.z, v.w};
        #pragma unroll
        for (int e = 0; e < 4; ++e) {
            int n = n4 * 4 + e;
            xl[n * 256 + ((chunk ^ n) * 8) + cl] = (_Float16)vv[e];
        }
    }

    float4v acc[5][2];
    const int obase = 80 * w;
    #pragma unroll
    for (int ot = 0; ot < 5; ++ot) {
        float4 b4 = *(const float4*)(bh + obase + 16 * ot + 4 * q);
        #pragma unroll
        for (int nt = 0; nt < 2; ++nt)
            acc[ot][nt] = (float4v){b4.x, b4.y, b4.z, b4.w};
    }
    __syncthreads();

    #pragma unroll
    for (int k = 0; k < 8; ++k) {
        half8 af[5], bf[2];
        #pragma unroll
        for (int ot = 0; ot < 5; ++ot)
            af[ot] = *(const half8*)(Wh + (size_t)(obase + 16 * ot + i16) * CC + k * 32 + 8 * q);
        #pragma unroll
        for (int nt = 0; nt < 2; ++nt) {
            int n = 16 * nt + i16;
            bf[nt] = *(const half8*)&xl[n * 256 + (((4 * k + q) ^ n) * 8)];
        }
        #pragma unroll
        for (int ot = 0; ot < 5; ++ot)
            #pragma unroll
            for (int nt = 0; nt < 2; ++nt)
                acc[ot][nt] = __builtin_amdgcn_mfma_f32_16x16x32_f16(af[ot], bf[nt], acc[ot][nt], 0, 0, 0);
    }

    #pragma unroll
    for (int ot = 0; ot < 5; ++ot) {
        int og = obase + 16 * ot;
        #pragma unroll
        for (int nt = 0; nt < 2; ++nt) {
            int n = 16 * nt + i16;
            if (og < 64) {
                half4 hv = { (_Float16)acc[ot][nt][0], (_Float16)acc[ot][nt][1],
                             (_Float16)acc[ot][nt][2], (_Float16)acc[ot][nt][3] };
                *(half4*)&os_qk[n * 72 + og + 4 * q] = hv;
            } else {
                int cb = og - 64 + 4 * q;
                #pragma unroll
                for (int r = 0; r < 4; ++r)
                    os_v[(cb + r) * 40 + n] = (_Float16)acc[ot][nt][r];
            }
        }
    }
    __syncthreads();

    _Float16* Qtb = Qt + (size_t)b * NN * DQ;
    _Float16* Ktb = Kt + (size_t)b * NN * DQ;
    {
        int n = tid >> 3, p = tid & 7;
        half8 hv = *(const half8*)&os_qk[n * 72 + 8 * p];
        if (p < 4) *(half8*)(Qtb + (size_t)(n0 + n) * DQ + 8 * p) = hv;
        else       *(half8*)(Ktb + (size_t)(n0 + n) * DQ + 8 * (p - 4)) = hv;
    }
    _Float16* Vb = Vh + (size_t)b * CC * NN;
    #pragma unroll
    for (int u = 0; u < 4; ++u) {
        int c = u * 64 + (tid >> 2), p = tid & 3;
        half8 hv = *(const half8*)&os_v[c * 40 + 8 * p];
        *(half8*)(Vb + (size_t)c * NN + n0 + 8 * p) = hv;
    }
}

// ---------------- rowstat: barrier-free, LDS-free streaming ----------------
// Per wave: 16 queries x 1024-key quarter, K loaded directly as A-fragments
// (coalesced 1KB/wave), 4-deep prefetch. No max-rescale: l = sum exp2(s)
// with reference 0 (|S2|max ~46 -> sum < 2^58, f32-safe). m tracked by fmax.
// M2/L: [b][4][N] f32 (L holds raw reference-0 sums).
__global__ __launch_bounds__(256) void rowstat_kernel(
    const _Float16* __restrict__ Qt, const _Float16* __restrict__ Kt,
    float* __restrict__ M2, float* __restrict__ L)
{
    const int tid = threadIdx.x;
    const int lane = tid & 63, w = tid >> 6;
    const int i16 = lane & 15, q = lane >> 4;
    const int q0 = blockIdx.x * 64, js = blockIdx.y, b = blockIdx.z;

    const _Float16* Qtb = Qt + (size_t)b * NN * DQ;
    const _Float16* kb  = Kt + (size_t)b * NN * DQ + (size_t)(js * 1024) * DQ;
    half8 qb = *(const half8*)(Qtb + (size_t)(q0 + 16 * w + i16) * DQ + 8 * q);

    half8 ka[4];
    #pragma unroll
    for (int u = 0; u < 4; ++u)
        ka[u] = *(const half8*)(kb + (size_t)(16 * u + i16) * DQ + 8 * q);

    float m = -INFINITY, l = 0.f;
    for (int t = 0; t < 64; t += 4) {
        #pragma unroll
        for (int u = 0; u < 4; ++u) {
            float4v z = {0.f, 0.f, 0.f, 0.f};
            float4v s = __builtin_amdgcn_mfma_f32_16x16x32_f16(ka[u], qb, z, 0, 0, 0);
            int nt = t + 4 + u;
            if (nt < 64)
                ka[u] = *(const half8*)(kb + (size_t)(16 * nt + i16) * DQ + 8 * q);
            m = fmaxf(m, fmaxf(fmaxf(s[0], s[1]), fmaxf(s[2], s[3])));
            l += (exp2f(s[0]) + exp2f(s[1])) + (exp2f(s[2]) + exp2f(s[3]));
        }
    }
    // combine the 4 quads (same query, different key rows): plain add / max
    l += __shfl_xor(l, 16, 64);
    l += __shfl_xor(l, 32, 64);
    m = fmaxf(m, __shfl_xor(m, 16, 64));
    m = fmaxf(m, __shfl_xor(m, 32, 64));
    if (q == 0) {
        int qi = q0 + 16 * w + i16;
        M2[((size_t)b * 4 + js) * NN + qi] = m;
        L[((size_t)b * 4 + js) * NN + qi] = l;
    }
}

// ---------------- attn: P software-pipelined one tile, 1 barrier/iter ----------------
// Block: 64 queries x 128 channels, 4 waves. Iter t: stage tile t+1 (K dbuf,
// V 3-buf), PV consumes ps[(t-1)&1] + V tile t-1 (both barrier-ready), S(t)
// writes ps[t&1]. Hazards: buf X written at iter t (post-barrier t); last
// read of X was pre-barrier(t) for all three buffers -> 1 syncthreads/iter.
__global__ __launch_bounds__(256) void attn_kernel(
    const float* __restrict__ x,
    const _Float16* __restrict__ Qt, const _Float16* __restrict__ Kt,
    const _Float16* __restrict__ Vh,
    const float* __restrict__ M2, const float* __restrict__ L,
    float* __restrict__ out)
{
    __shared__ _Float16 k_lds[2][64 * 32];    // [j][d], d-chunk ^= (j&3)
    __shared__ _Float16 v_lds[3][128 * 64];   // [c][j], j-chunk ^= (c&7)
    __shared__ _Float16 ps[2][64 * 72];       // P': [i][j + pad]

    const int tid = threadIdx.x;
    const int w = tid >> 6, lane = tid & 63;
    const int i16 = lane & 15, q = lane >> 4;
    const int i0 = blockIdx.x * 64, cs = blockIdx.y, b = blockIdx.z;
    const int c0 = cs * 128;

    const _Float16* Ktb = Kt + (size_t)b * NN * DQ;
    const _Float16* Vb  = Vh + (size_t)b * CC * NN + (size_t)c0 * NN;

    // combine the 4 j-quarters: m = max, l = plain sum (reference-0 sums)
    float m2v[4], linv[4];
    #pragma unroll
    for (int it = 0; it < 4; ++it) {
        int qi = i0 + 16 * it + i16;
        float mm = -INFINITY, ll = 0.f;
        #pragma unroll
        for (int p = 0; p < 4; ++p) {
            mm = fmaxf(mm, M2[((size_t)b * 4 + p) * NN + qi]);
            ll += L[((size_t)b * 4 + p) * NN + qi];
        }
        m2v[it] = mm;
        linv[it] = exp2f(mm) / ll;   // 1 / sum_j exp2(s_j - mm)
    }

    half8 qb[4];
    {
        const _Float16* Qtb = Qt + (size_t)b * NN * DQ;
        #pragma unroll
        for (int it = 0; it < 4; ++it)
            qb[it] = *(const half8*)(Qtb + (size_t)(i0 + 16 * it + i16) * DQ + 8 * q);
    }

    float4v O[2][4];
    #pragma unroll
    for (int ct = 0; ct < 2; ++ct)
        #pragma unroll
        for (int it = 0; it < 4; ++it)
            O[ct][it] = (float4v){0.f, 0.f, 0.f, 0.f};

    // staging addresses
    const int jK = tid >> 2, dgK = tid & 3;      // K: 1 half8/thread
    const int cbV = tid >> 3, jgV = tid & 7;     // V: 4 half8/thread
    const int kaddr = jK * 32 + ((dgK ^ (jK & 3)) * 8);
    int vaddr[4];
    #pragma unroll
    for (int u = 0; u < 4; ++u) {
        int c = u * 32 + cbV;
        vaddr[u] = c * 64 + ((jgV ^ (c & 7)) * 8);
    }

    // prologue: tile 0 -> buffers 0; tile 1 in regs
    half8 kv, vv[4];
    kv = *(const half8*)(Ktb + (size_t)jK * DQ + 8 * dgK);
    #pragma unroll
    for (int u = 0; u < 4; ++u)
        vv[u] = *(const half8*)(Vb + (size_t)(u * 32 + cbV) * NN + 8 * jgV);
    *(half8*)&k_lds[0][kaddr] = kv;
    #pragma unroll
    for (int u = 0; u < 4; ++u)
        *(half8*)&v_lds[0][vaddr[u]] = vv[u];
    kv = *(const half8*)(Ktb + (size_t)(64 + jK) * DQ + 8 * dgK);
    #pragma unroll
    for (int u = 0; u < 4; ++u)
        vv[u] = *(const half8*)(Vb + (size_t)(u * 32 + cbV) * NN + 64 + 8 * jgV);

    for (int t = 0; t <= 64; ++t) {
        __syncthreads();
        // stage tile t+1 from regs (loaded at iter t-1)
        if (t < 63) {
            *(half8*)&k_lds[(t + 1) & 1][kaddr] = kv;
            const int vn = (t + 1) % 3;
            #pragma unroll
            for (int u = 0; u < 4; ++u)
                *(half8*)&v_lds[vn][vaddr[u]] = vv[u];
        }
        // issue prefetch of tile t+2 (drained by next barrier; covers S+PV)
        if (t < 62) {
            int jn = (t + 2) * 64;
            kv = *(const half8*)(Ktb + (size_t)(jn + jK) * DQ + 8 * dgK);
            #pragma unroll
            for (int u = 0; u < 4; ++u)
                vv[u] = *(const half8*)(Vb + (size_t)(u * 32 + cbV) * NN + jn + 8 * jgV);
        }
        // PV(t-1): inputs were completed before this iter's barrier
        if (t > 0) {
            const _Float16* psp = ps[(t - 1) & 1];
            const _Float16* vp  = v_lds[(t - 1) % 3];
            half8 pb[2][4];
            #pragma unroll
            for (int ks = 0; ks < 2; ++ks)
                #pragma unroll
                for (int it = 0; it < 4; ++it)
                    pb[ks][it] = *(const half8*)&psp[(16 * it + i16) * 72 + 32 * ks + 8 * q];
            __builtin_amdgcn_s_setprio(1);
            #pragma unroll
            for (int ct = 0; ct < 2; ++ct) {
                int c = 32 * w + 16 * ct + i16;
                #pragma unroll
                for (int ks = 0; ks < 2; ++ks) {
                    int g = 4 * ks + q;
                    half8 va = *(const half8*)&vp[c * 64 + ((g ^ (c & 7)) * 8)];
                    #pragma unroll
                    for (int it = 0; it < 4; ++it)
                        O[ct][it] = __builtin_amdgcn_mfma_f32_16x16x32_f16(va, pb[ks][it], O[ct][it], 0, 0, 0);
                }
            }
            __builtin_amdgcn_s_setprio(0);
        }
        // S(t) -> ps[t&1]
        if (t < 64) {
            int j = 16 * w + i16;
            half8 ka = *(const half8*)&k_lds[t & 1][j * 32 + ((q ^ (j & 3)) * 8)];
            _Float16* psc = ps[t & 1];
            #pragma unroll
            for (int it = 0; it < 4; ++it) {
                float4v z = {0.f, 0.f, 0.f, 0.f};
                float4v s = __builtin_amdgcn_mfma_f32_16x16x32_f16(ka, qb[it], z, 0, 0, 0);
                half4 hv = { (_Float16)exp2f(s[0] - m2v[it]),
                             (_Float16)exp2f(s[1] - m2v[it]),
                             (_Float16)exp2f(s[2] - m2v[it]),
                             (_Float16)exp2f(s[3] - m2v[it]) };
                *(half4*)&psc[(16 * it + i16) * 72 + 16 * w + 4 * q] = hv;
            }
        }
    }

    // epilogue: O * (1/l) + residual
    const float* xb = x + (size_t)b * CC * NN;
    float* ob = out + (size_t)b * CC * NN;
    #pragma unroll
    for (int ct = 0; ct < 2; ++ct)
        #pragma unroll
        for (int it = 0; it < 4; ++it)
            #pragma unroll
            for (int r = 0; r < 4; ++r) {
                int c = c0 + 32 * w + 16 * ct + 4 * q + r;
                size_t idx = (size_t)c * NN + i0 + 16 * it + i16;
                ob[idx] = xb[idx] + O[ct][it][r] * linv[it];
            }
}

extern "C" void kernel_launch(void* const* d_in, const int* in_sizes, int n_in,
                              void* d_out, int out_size, void* d_ws, size_t ws_size,
                              hipStream_t stream) {
    const float* x  = (const float*)d_in[0];
    const float* Wq = (const float*)d_in[1];
    const float* bq = (const float*)d_in[2];
    const float* Wk = (const float*)d_in[3];
    const float* bk = (const float*)d_in[4];
    const float* Wv = (const float*)d_in[5];
    const float* bv = (const float*)d_in[6];
    float* out = (float*)d_out;

    char* ws = (char*)d_ws;
    _Float16* Wh = (_Float16*)(ws);                 // 320*256*2 = 163840
    float*    bh = (float*)(ws + 163840);           // 1280
    _Float16* Qt = (_Float16*)(ws + 262144);        // 4*4096*32*2 = 1 MB
    _Float16* Kt = (_Float16*)(ws + 1310720);       // 1 MB
    _Float16* Vh = (_Float16*)(ws + 2359296);       // 4*256*4096*2 = 8 MB
    float*    M2 = (float*)(ws + 10747904);         // 4*4*4096*4 = 256 KB
    float*    L  = (float*)(ws + 11010048);         // 256 KB

    prep_kernel<<<dim3(320), 64, 0, stream>>>(Wq, bq, Wk, bk, Wv, bv, Wh, bh);
    proj_kernel<<<dim3(NN / 32, BB), 256, 0, stream>>>(x, Wh, bh, Qt, Kt, Vh);
    rowstat_kernel<<<dim3(NN / 64, 4, BB), 256, 0, stream>>>(Qt, Kt, M2, L);
    attn_kernel<<<dim3(NN / 64, 2, BB), 256, 0, stream>>>(x, Qt, Kt, Vh, M2, L, out);
}